// Round 21
// baseline (267.188 us; speedup 1.0000x reference)
//
#include <hip/hip_runtime.h>
#include <hip/hip_cooperative_groups.h>
#include <hip/hip_bf16.h>
#include <math.h>

namespace cg = cooperative_groups;

typedef __hip_bfloat16 bf16;
typedef __attribute__((ext_vector_type(8))) short short8;
typedef __attribute__((ext_vector_type(4))) float f32x4;

__device__ __forceinline__ bf16 f2b(float v){ return __float2bfloat16(v); }
__device__ __forceinline__ float ldf(float v){ return v; }
__device__ __forceinline__ float ldf(bf16 v){ return __bfloat162float(v); }
__device__ __forceinline__ unsigned short fbits(float v){
  __hip_bfloat16 h = __float2bfloat16(v);
  return *reinterpret_cast<unsigned short*>(&h);
}
__device__ __forceinline__ float dot4(float4 a, float4 b){
  return fmaf(a.x,b.x, fmaf(a.y,b.y, fmaf(a.z,b.z, a.w*b.w)));
}
__device__ __forceinline__ void load_lds16(const bf16* src, void* lds){
  __builtin_amdgcn_global_load_lds(
      (const __attribute__((address_space(1))) void*)src,
      (__attribute__((address_space(3))) void*)lds, 16, 0, 0);
}

// ---------- node mask dtype helpers (prefix mask)
__device__ __forceinline__ int mask_mode(const void* p){
  unsigned w0 = ((const unsigned*)p)[0];
  unsigned w1 = ((const unsigned*)p)[1];
  if(w0 == 1u) return (w1 == 0u) ? 4 : 0;
  if(w0 == 0x3F800000u) return 3;
  unsigned short h0 = (unsigned short)(w0 & 0xFFFFu);
  if(h0 == 0x3F80u || h0 == 0x3C00u) return 2;
  return 1;
}
__device__ __forceinline__ int mask_get(const void* p, int i, int mode){
  switch(mode){
    case 0: return ((const int*)p)[i] != 0;
    case 1: return ((const unsigned char*)p)[i] != 0;
    case 2: return ((const unsigned short*)p)[i] != 0;
    case 3: return ((const float*)p)[i] != 0.f;
    default: return ((const long long*)p)[i] != 0ll;
  }
}

// ---------- fused: conv1 (blocks 0..1023) + weight transforms + LUT (blocks 1024..2551)
__global__ __launch_bounds__(256) void k_c1prep(const float* __restrict__ img,
                        const float* __restrict__ c1w, const float* __restrict__ c1b,
                        bf16* __restrict__ x1,
                        const float* __restrict__ c2w, const float* __restrict__ c3w,
                        const float* __restrict__ c4w, bf16* __restrict__ wt2,
                        bf16* __restrict__ wt3, bf16* __restrict__ wt4,
                        const float* __restrict__ w1, const float* __restrict__ b1,
                        const float* __restrict__ w2, const float* __restrict__ b2,
                        const float* __restrict__ w3, const float* __restrict__ b3,
                        float* __restrict__ lut){
  int bid = blockIdx.x;
  int tid = threadIdx.x;
  if(bid >= 1024){
    int pb = bid - 1024;
    if(pb < 1512){
      int e = pb*256 + tid;
      const float* w; bf16* wt; int OC, IC;
      if(e < 18432){ w = c2w; wt = wt2; OC = 64;  IC = 32; }
      else if(e < 92160){ e -= 18432; w = c3w; wt = wt3; OC = 128; IC = 64; }
      else { e -= 92160; w = c4w; wt = wt4; OC = 256; IC = 128; }
      int ic = e % IC; int t2 = e / IC; int oc = t2 % OC; int tap = t2 / OC;
      wt[e] = f2b(w[(oc*IC + ic)*9 + tap]);
    } else {
      int e = (pb-1512)*256 + tid;
      float s = -1.f + (2.f/4095.f)*e;
      float h1[32];
      #pragma unroll
      for(int k=0;k<32;k++) h1[k] = fmaxf(fmaf(s, w1[k], b1[k]), 0.f);
      float a3 = b3[0];
      #pragma unroll
      for(int j=0;j<16;j++){
        float t = b2[j];
        #pragma unroll
        for(int k=0;k<32;k++) t = fmaf(h1[k], w2[j*32+k], t);
        a3 = fmaf(fmaxf(t,0.f), w3[j], a3);
      }
      lut[e] = 1.f/(1.f + expf(-a3));
    }
    return;
  }
  __shared__ float Wl[288], Bl[32];
  for(int t=tid; t<288; t+=256) Wl[t] = c1w[t];
  if(tid<32) Bl[tid] = c1b[tid];
  __syncthreads();
  int idx = bid*256 + tid;
  int ox = idx & 127, oy = (idx>>7)&127, b = idx>>14;
  const float4* ip4 = (const float4*)(img + (size_t)b*65536);   // [256][64] float4
  int y0 = oy*2-1;
  int a  = (2*ox - 1) >> 2;          // arithmetic: ox=0 -> -1
  bool odd = (ox & 1);               // in-vector offset 1 (odd) or 3 (even)
  float patch[4][4];
  #pragma unroll
  for(int py=0;py<4;py++){
    int y = y0+py; bool yok = (unsigned)y<256u;
    float4 A = make_float4(0.f,0.f,0.f,0.f), B = make_float4(0.f,0.f,0.f,0.f);
    if(yok && a >= 0) A = ip4[y*64 + a];
    if(yok && a < 63) B = ip4[y*64 + a + 1];
    patch[py][0] = odd ? A.y : A.w;
    patch[py][1] = odd ? A.z : B.x;
    patch[py][2] = odd ? A.w : B.y;
    patch[py][3] = odd ? B.x : B.z;
  }
  unsigned u[16];
  #pragma unroll
  for(int og=0; og<16; og++){
    unsigned short hb[2];
    #pragma unroll
    for(int h=0; h<2; h++){
      int oc = og*2 + h;
      const float* wj = &Wl[oc*9];
      float best = 0.f;
      #pragma unroll
      for(int py=0;py<2;py++)
      #pragma unroll
      for(int px=0;px<2;px++){
        float a2 = Bl[oc];
        #pragma unroll
        for(int ky=0;ky<3;ky++)
        #pragma unroll
        for(int kx=0;kx<3;kx++)
          a2 = fmaf(wj[ky*3+kx], patch[py+ky][px+kx], a2);
        best = fmaxf(best, a2);
      }
      hb[h] = fbits(best);
    }
    u[og] = (unsigned)hb[0] | ((unsigned)hb[1] << 16);
  }
  uint4* dst = (uint4*)(x1 + (size_t)idx*32);
  dst[0] = make_uint4(u[0],u[1],u[2],u[3]);
  dst[1] = make_uint4(u[4],u[5],u[6],u[7]);
  dst[2] = make_uint4(u[8],u[9],u[10],u[11]);
  dst[3] = make_uint4(u[12],u[13],u[14],u[15]);
}

// ---------- MFMA tap-loop implicit-GEMM conv (R12 geometry; global_load_lds staging;
//            s_setprio(1) around each 16-MFMA cluster -- T5)
template<int L>
__global__ __launch_bounds__(256) void k_convmfma(const bf16* __restrict__ in,
                      const bf16* __restrict__ wt, const float* __restrict__ bias,
                      bf16* __restrict__ out, float* __restrict__ partial2){
  constexpr int IC   = L==2?32:(L==3?64:128);
  constexpr int OC   = L==2?64:(L==3?128:256);
  constexpr int HW   = L==2?128:(L==3?64:32);
  constexpr int POOL = L==4?0:1;
  constexpr int WNF  = L==4?2:4;
  constexpr int IC8  = IC/8;
  constexpr int SM   = (IC8-1)&7;
  constexpr int KC   = IC/32;
  constexpr int XT   = HW;
  constexpr int ROW  = XT*IC8;
  constexpr int ROWC = (XT+2)*IC8;
  __shared__ short8 T[4*ROWC];

  int bid = blockIdx.x;
  int b, py, bt = 0;
  if(L==4){ b = bid>>5; py = (bid>>1)&15; bt = bid&1; }
  else if(L==3){ b = bid>>5; py = bid&31; }
  else { b = bid>>6; py = bid&63; }

  int tid = threadIdx.x;
  int w = tid>>6, l15 = tid&15, lhi = (tid>>4)&3, lane = tid&63;

  int mbase, nbase;
  if(L==2){ mbase = w*32; nbase = 0; }
  else if(L==3){ mbase = (w&1)*32; nbase = (w>>1)*64; }
  else { mbase = 0; nbase = bt*128 + w*32; }

  for(int c=tid; c<4*2*IC8; c+=256){
    int r = c/(2*IC8), rem = c%(2*IC8);
    int X = (rem>=IC8)?(XT+1):0;
    int k = rem%IC8;
    short8 z = {0,0,0,0,0,0,0,0};
    T[(r*(XT+2)+X)*IC8 + k] = z;
  }
  for(int c0=0; c0<4*ROW; c0+=256){
    int cw  = c0 + w*64;
    int r   = cw / ROW;
    int rem = cw % ROW;
    int gy  = 2*py - 1 + r;
    int ldsbase = (r*(XT+2)+1)*IC8 + rem;
    if((unsigned)gy < (unsigned)HW){
      int remL = rem + lane;
      int x = remL / IC8, k = remL % IC8;
      int ksrc = k ^ ((x+1)&SM);
      const bf16* src = in + (((size_t)b*HW + gy)*XT + x)*IC + ksrc*8;
      load_lds16(src, (void*)&T[ldsbase]);
    } else {
      short8 z = {0,0,0,0,0,0,0,0};
      T[ldsbase + lane] = z;
    }
  }
  __syncthreads();

  float bv[WNF];
  #pragma unroll
  for(int n=0;n<WNF;n++) bv[n] = bias[nbase + n*16 + l15];
  f32x4 acc[2][2][WNF];
  #pragma unroll
  for(int r=0;r<2;r++)
  #pragma unroll
  for(int m=0;m<2;m++)
  #pragma unroll
  for(int n=0;n<WNF;n++){
    acc[r][m][n][0]=bv[n]; acc[r][m][n][1]=bv[n];
    acc[r][m][n][2]=bv[n]; acc[r][m][n][3]=bv[n];
  }

  const short8* wt8 = (const short8*)wt;
  #pragma unroll
  for(int tap=0; tap<9; tap++){
    const int dy = tap/3 - 1, dx = tap%3 - 1;
    #pragma unroll
    for(int kc=0; kc<KC; kc++){
      short8 Bf[WNF];
      #pragma unroll
      for(int n=0;n<WNF;n++){
        int oc = nbase + n*16 + l15;
        Bf[n] = wt8[(size_t)(tap*OC + oc)*IC8 + kc*4 + lhi];
      }
      short8 Af[2][2];
      #pragma unroll
      for(int r=0;r<2;r++)
      #pragma unroll
      for(int m=0;m<2;m++){
        int X = mbase + m*16 + l15 + dx + 1;
        int rs = r + dy + 1;
        Af[r][m] = T[(rs*(XT+2)+X)*IC8 + ((kc*4+lhi) ^ (X&SM))];
      }
      __builtin_amdgcn_s_setprio(1);
      #pragma unroll
      for(int r=0;r<2;r++)
      #pragma unroll
      for(int m=0;m<2;m++)
      #pragma unroll
      for(int n=0;n<WNF;n++)
        acc[r][m][n] = __builtin_amdgcn_mfma_f32_16x16x32_bf16(Af[r][m], Bf[n], acc[r][m][n], 0,0,0);
      __builtin_amdgcn_s_setprio(0);
    }
  }

  if(POOL){
    constexpr int HP = HW/2;
    #pragma unroll
    for(int m=0;m<2;m++)
    #pragma unroll
    for(int n=0;n<WNF;n++){
      int oc = nbase + n*16 + l15;
      #pragma unroll
      for(int t=0;t<2;t++){
        float v = fmaxf(fmaxf(acc[0][m][n][2*t], acc[0][m][n][2*t+1]),
                        fmaxf(acc[1][m][n][2*t], acc[1][m][n][2*t+1]));
        v = fmaxf(v, 0.f);
        int xp = (mbase + m*16)/2 + lhi*2 + t;
        out[(((size_t)b*HP + py)*HP + xp)*OC + oc] = f2b(v);
      }
    }
  } else {
    #pragma unroll
    for(int n=0;n<WNF;n++){
      float p = 0.f;
      #pragma unroll
      for(int r=0;r<2;r++)
      #pragma unroll
      for(int m=0;m<2;m++)
      #pragma unroll
      for(int j=0;j<4;j++)
        p += fmaxf(acc[r][m][n][j], 0.f);
      p += __shfl_xor(p, 16);
      p += __shfl_xor(p, 32);
      if(lhi == 0)
        partial2[((size_t)(b*16+py))*256 + nbase + n*16 + l15] = p;
    }
  }
}

// ---------- cooperative tail: headA -> grid.sync -> headB -> grid.sync -> adj
__global__ __launch_bounds__(256, 4) void k_tail(
    const float* __restrict__ partial2, const void* __restrict__ masks,
    const float* __restrict__ nd1w, const float* __restrict__ nd1b,
    const float* __restrict__ cp1w, const float* __restrict__ cp1b,
    const float* __restrict__ nd2w, const float* __restrict__ nd2b,
    const float* __restrict__ cp2w, const float* __restrict__ cp2b,
    const float* __restrict__ lut,
    float* __restrict__ h512, float* __restrict__ h256,
    float* __restrict__ coordsOut, float* __restrict__ countOut,
    int* __restrict__ counts){
  cg::grid_group grid = cg::this_grid();
  __shared__ float F[256];
  int tid = threadIdx.x;
  int w = tid>>6, lane = tid&63;

  // ---- Phase A: headA, 3072 units over 1024 blocks (3 each)
  for(int u = blockIdx.x; u < 3072; u += 1024){
    int b = u / 192, blk = u % 192;
    float s = 0.f;
    #pragma unroll
    for(int q=0;q<16;q++) s += partial2[((size_t)(b*16+q))*256 + tid];
    F[tid] = s * (1.f/1024.f);
    __syncthreads();
    int o = blk*4 + w;
    float4 xv = ((const float4*)F)[lane];
    const float* wrow; float bb; float* dst; int oo;
    if(o < 512){ wrow = nd1w + (size_t)o*256; bb = nd1b[o]; dst = h512 + b*512 + o; }
    else { oo = o - 512; wrow = cp1w + (size_t)oo*256; bb = cp1b[oo]; dst = h256 + b*256 + oo; }
    float a = dot4(((const float4*)wrow)[lane], xv);
    #pragma unroll
    for(int off=32; off>0; off>>=1) a += __shfl_xor(a, off);
    if(lane==0) *dst = fmaxf(a + bb, 0.f);
    __syncthreads();   // protect F before next grid-stride iteration
  }
  grid.sync();

  // ---- Phase B: headB, 2816 units over 1024 blocks
  for(int u = blockIdx.x; u < 2816; u += 1024){
    int b = u / 176, blk = u % 176;
    int o = blk*4 + w;
    if(o == 701){
      int mode = mask_mode(masks);
      int c = 0;
      for(int i=lane; i<350; i+=64) c += mask_get(masks, b*350+i, mode);
      #pragma unroll
      for(int off=32; off>0; off>>=1) c += __shfl_xor(c, off);
      if(lane==0) counts[b] = c;
      continue;
    }
    if(o > 700) continue;
    float a;
    if(o < 700){
      const float4* xp = (const float4*)(h512 + b*512);
      const float4* wp = (const float4*)(nd2w + (size_t)o*512);
      a = dot4(wp[lane], xp[lane]) + dot4(wp[lane+64], xp[lane+64]);
    } else {
      const float4* xp = (const float4*)(h256 + b*256);
      const float4* wp = (const float4*)cp2w;
      a = dot4(wp[lane], xp[lane]);
    }
    #pragma unroll
    for(int off=32; off>0; off>>=1) a += __shfl_xor(a, off);
    if(lane==0){
      if(o < 700) coordsOut[b*700 + o] = a + nd2b[o];
      else        countOut[b] = a + cp2b[0];
    }
  }
  grid.sync();

  // ---- Phase C: adj, 1915 block-units over 1024 blocks
  for(int u = blockIdx.x; u < 1915; u += 1024){
    int t4 = u*256 + tid;
    if(t4 >= 490000) continue;
    int base = t4*4;
    int b = base / 122500;
    int rem = base % 122500;      // 122500 % 4 == 0: all 4 elems share b
    int cnt = counts[b];
    int valid = cnt > 1;
    float res[4];
    #pragma unroll
    for(int e=0;e<4;e++){
      int n = (rem+e)/350, m = (rem+e)%350;
      float o = 0.f;
      if(valid && n < cnt && m < cnt){
        float2 a = ((const float2*)coordsOut)[b*350+n];
        float2 c = ((const float2*)coordsOut)[b*350+m];
        float nn = fmaxf(fmaf(a.x,a.x, a.y*a.y), 1e-24f);
        float mm = fmaxf(fmaf(c.x,c.x, c.y*c.y), 1e-24f);
        float s = fmaf(a.x, c.x, a.y*c.y) * __frsqrt_rn(nn) * __frsqrt_rn(mm);
        float uu = (s + 1.f) * 2047.5f;
        uu = fminf(fmaxf(uu, 0.f), 4095.f);
        int i = min((int)uu, 4094);
        float fr = uu - (float)i;
        float l0 = lut[i], l1 = lut[i+1];
        o = fmaf(l1 - l0, fr, l0);
      }
      res[e] = o;
    }
    *(float4*)(coordsOut + 11200 + base) = make_float4(res[0], res[1], res[2], res[3]);
  }
}

extern "C" void kernel_launch(void* const* d_in, const int* in_sizes, int n_in,
                              void* d_out, int out_size, void* d_ws, size_t ws_size,
                              hipStream_t stream){
  const float* images = (const float*)d_in[0];
  const void*  masks  = d_in[1];
  const float *c1w=(const float*)d_in[2],  *c1b=(const float*)d_in[3];
  const float *c2w=(const float*)d_in[4],  *c2b=(const float*)d_in[5];
  const float *c3w=(const float*)d_in[6],  *c3b=(const float*)d_in[7];
  const float *c4w=(const float*)d_in[8],  *c4b=(const float*)d_in[9];
  const float *nd1w=(const float*)d_in[10],*nd1b=(const float*)d_in[11];
  const float *nd2w=(const float*)d_in[12],*nd2b=(const float*)d_in[13];
  const float *cp1w=(const float*)d_in[14],*cp1b=(const float*)d_in[15];
  const float *cp2w=(const float*)d_in[16],*cp2b=(const float*)d_in[17];
  const float *mc1w=(const float*)d_in[18],*mc1b=(const float*)d_in[19];
  const float *mc2w=(const float*)d_in[20],*mc2b=(const float*)d_in[21];
  const float *mc3w=(const float*)d_in[22],*mc3b=(const float*)d_in[23];
  float* out = (float*)d_out;   // f32: coords[11200] | adjacency[1960000] | count[16]

  // ---- workspace
  char* W = (char*)d_ws;
  float* partial2 = (float*)W;                  // 256 rows x 256 f32 = 256 KB @0
  float* h512     = (float*)(W + 262144);       // 8192 f32 (32 KB)
  float* h256     = (float*)(W + 294912);       // 4096 f32 (16 KB)
  float* lut      = (float*)(W + 311296);       // 4096 f32 (16 KB)
  int*   counts   = (int*)(W + 327680);         // 64 B
  bf16*  wt2 = (bf16*)(W + 524288);             // 18432 bf16 (36 KB)
  bf16*  wt3 = (bf16*)(W + 589824);             // 73728 bf16 (144 KB)
  bf16*  wt4 = (bf16*)(W + 786432);             // 294912 bf16 (576 KB)
  bf16*  x1 = (bf16*)(W + 2097152);             // [16][128][128][32] 16.78 MB
  bf16*  x2 = (bf16*)(W + 2097152 + 16777216);  // [16][64][64][64]    8.39 MB
  bf16*  x3 = (bf16*)(W + 2097152);             // [16][32][32][128]   4.19 MB (reuse x1)

  float* coordsOut = out;
  float* countOut  = out + 11200 + 1960000;

  k_c1prep<<<2552, 256, 0, stream>>>(images, c1w, c1b, x1,
                                     c2w, c3w, c4w, wt2, wt3, wt4,
                                     mc1w, mc1b, mc2w, mc2b, mc3w, mc3b, lut);
  k_convmfma<2><<<1024, 256, 0, stream>>>(x1, wt2, c2b, x2, nullptr);
  k_convmfma<3><<<512, 256, 0, stream>>>(x2, wt3, c3b, x3, nullptr);
  k_convmfma<4><<<512, 256, 0, stream>>>(x3, wt4, c4b, nullptr, partial2);

  void* args[] = {
    (void*)&partial2, (void*)&masks,
    (void*)&nd1w, (void*)&nd1b, (void*)&cp1w, (void*)&cp1b,
    (void*)&nd2w, (void*)&nd2b, (void*)&cp2w, (void*)&cp2b,
    (void*)&lut, (void*)&h512, (void*)&h256,
    (void*)&coordsOut, (void*)&countOut, (void*)&counts
  };
  hipLaunchCooperativeKernel((const void*)k_tail, dim3(1024), dim3(256),
                             args, 0, stream);
}

// Round 22
// 92.577 us; speedup vs baseline: 2.8861x; 2.8861x over previous
//
#include <hip/hip_runtime.h>
#include <hip/hip_bf16.h>
#include <math.h>

typedef __hip_bfloat16 bf16;
typedef __attribute__((ext_vector_type(8))) short short8;
typedef __attribute__((ext_vector_type(4))) float f32x4;

__device__ __forceinline__ bf16 f2b(float v){ return __float2bfloat16(v); }
__device__ __forceinline__ float ldf(float v){ return v; }
__device__ __forceinline__ float ldf(bf16 v){ return __bfloat162float(v); }
__device__ __forceinline__ unsigned short fbits(float v){
  __hip_bfloat16 h = __float2bfloat16(v);
  return *reinterpret_cast<unsigned short*>(&h);
}
__device__ __forceinline__ float dot4(float4 a, float4 b){
  return fmaf(a.x,b.x, fmaf(a.y,b.y, fmaf(a.z,b.z, a.w*b.w)));
}
__device__ __forceinline__ void load_lds16(const bf16* src, void* lds){
  __builtin_amdgcn_global_load_lds(
      (const __attribute__((address_space(1))) void*)src,
      (__attribute__((address_space(3))) void*)lds, 16, 0, 0);
}

// ---------- fused: conv1 (blocks 0..1023) + weight transforms + LUT (blocks 1024..2551)
__global__ __launch_bounds__(256) void k_c1prep(const float* __restrict__ img,
                        const float* __restrict__ c1w, const float* __restrict__ c1b,
                        bf16* __restrict__ x1,
                        const float* __restrict__ c2w, const float* __restrict__ c3w,
                        const float* __restrict__ c4w, bf16* __restrict__ wt2,
                        bf16* __restrict__ wt3, bf16* __restrict__ wt4,
                        const float* __restrict__ w1, const float* __restrict__ b1,
                        const float* __restrict__ w2, const float* __restrict__ b2,
                        const float* __restrict__ w3, const float* __restrict__ b3,
                        float* __restrict__ lut){
  int bid = blockIdx.x;
  int tid = threadIdx.x;
  if(bid >= 1024){
    int pb = bid - 1024;
    if(pb < 1512){
      int e = pb*256 + tid;
      const float* w; bf16* wt; int OC, IC;
      if(e < 18432){ w = c2w; wt = wt2; OC = 64;  IC = 32; }
      else if(e < 92160){ e -= 18432; w = c3w; wt = wt3; OC = 128; IC = 64; }
      else { e -= 92160; w = c4w; wt = wt4; OC = 256; IC = 128; }
      int ic = e % IC; int t2 = e / IC; int oc = t2 % OC; int tap = t2 / OC;
      wt[e] = f2b(w[(oc*IC + ic)*9 + tap]);
    } else {
      int e = (pb-1512)*256 + tid;
      float s = -1.f + (2.f/4095.f)*e;
      float h1[32];
      #pragma unroll
      for(int k=0;k<32;k++) h1[k] = fmaxf(fmaf(s, w1[k], b1[k]), 0.f);
      float a3 = b3[0];
      #pragma unroll
      for(int j=0;j<16;j++){
        float t = b2[j];
        #pragma unroll
        for(int k=0;k<32;k++) t = fmaf(h1[k], w2[j*32+k], t);
        a3 = fmaf(fmaxf(t,0.f), w3[j], a3);
      }
      lut[e] = 1.f/(1.f + expf(-a3));
    }
    return;
  }
  __shared__ float Wl[288], Bl[32];
  for(int t=tid; t<288; t+=256) Wl[t] = c1w[t];
  if(tid<32) Bl[tid] = c1b[tid];
  __syncthreads();
  int idx = bid*256 + tid;
  int ox = idx & 127, oy = (idx>>7)&127, b = idx>>14;
  const float4* ip4 = (const float4*)(img + (size_t)b*65536);   // [256][64] float4
  int y0 = oy*2-1;
  int a  = (2*ox - 1) >> 2;          // arithmetic: ox=0 -> -1
  bool odd = (ox & 1);               // in-vector offset 1 (odd) or 3 (even)
  float patch[4][4];
  #pragma unroll
  for(int py=0;py<4;py++){
    int y = y0+py; bool yok = (unsigned)y<256u;
    float4 A = make_float4(0.f,0.f,0.f,0.f), B = make_float4(0.f,0.f,0.f,0.f);
    if(yok && a >= 0) A = ip4[y*64 + a];
    if(yok && a < 63) B = ip4[y*64 + a + 1];
    patch[py][0] = odd ? A.y : A.w;
    patch[py][1] = odd ? A.z : B.x;
    patch[py][2] = odd ? A.w : B.y;
    patch[py][3] = odd ? B.x : B.z;
  }
  unsigned u[16];
  #pragma unroll
  for(int og=0; og<16; og++){
    unsigned short hb[2];
    #pragma unroll
    for(int h=0; h<2; h++){
      int oc = og*2 + h;
      const float* wj = &Wl[oc*9];
      float best = 0.f;
      #pragma unroll
      for(int py=0;py<2;py++)
      #pragma unroll
      for(int px=0;px<2;px++){
        float a2 = Bl[oc];
        #pragma unroll
        for(int ky=0;ky<3;ky++)
        #pragma unroll
        for(int kx=0;kx<3;kx++)
          a2 = fmaf(wj[ky*3+kx], patch[py+ky][px+kx], a2);
        best = fmaxf(best, a2);
      }
      hb[h] = fbits(best);
    }
    u[og] = (unsigned)hb[0] | ((unsigned)hb[1] << 16);
  }
  uint4* dst = (uint4*)(x1 + (size_t)idx*32);
  dst[0] = make_uint4(u[0],u[1],u[2],u[3]);
  dst[1] = make_uint4(u[4],u[5],u[6],u[7]);
  dst[2] = make_uint4(u[8],u[9],u[10],u[11]);
  dst[3] = make_uint4(u[12],u[13],u[14],u[15]);
}

// ---------- MFMA tap-loop implicit-GEMM conv (R12 geometry; global_load_lds staging;
//            s_setprio(1) around each 16-MFMA cluster -- T5)
// L=2: 32->64 @128, pool (grid 1024). L=3: 64->128 @64, pool (grid 512).
// L=4: 128->256 @32, no pool, fused relu+spatial-sum -> partial2 (grid 512)
template<int L>
__global__ __launch_bounds__(256) void k_convmfma(const bf16* __restrict__ in,
                      const bf16* __restrict__ wt, const float* __restrict__ bias,
                      bf16* __restrict__ out, float* __restrict__ partial2){
  constexpr int IC   = L==2?32:(L==3?64:128);
  constexpr int OC   = L==2?64:(L==3?128:256);
  constexpr int HW   = L==2?128:(L==3?64:32);
  constexpr int POOL = L==4?0:1;
  constexpr int WNF  = L==4?2:4;
  constexpr int IC8  = IC/8;
  constexpr int SM   = (IC8-1)&7;
  constexpr int KC   = IC/32;
  constexpr int XT   = HW;
  constexpr int ROW  = XT*IC8;         // interior chunks per LDS row (64-aligned)
  constexpr int ROWC = (XT+2)*IC8;
  __shared__ short8 T[4*ROWC];

  int bid = blockIdx.x;
  int b, py, bt = 0;
  if(L==4){ b = bid>>5; py = (bid>>1)&15; bt = bid&1; }
  else if(L==3){ b = bid>>5; py = bid&31; }
  else { b = bid>>6; py = bid&63; }

  int tid = threadIdx.x;
  int w = tid>>6, l15 = tid&15, lhi = (tid>>4)&3, lane = tid&63;

  int mbase, nbase;
  if(L==2){ mbase = w*32; nbase = 0; }
  else if(L==3){ mbase = (w&1)*32; nbase = (w>>1)*64; }
  else { mbase = 0; nbase = bt*128 + w*32; }

  // halo columns X=0, X=XT+1: genuinely out-of-image -> zeros
  for(int c=tid; c<4*2*IC8; c+=256){
    int r = c/(2*IC8), rem = c%(2*IC8);
    int X = (rem>=IC8)?(XT+1):0;
    int k = rem%IC8;
    short8 z = {0,0,0,0,0,0,0,0};
    T[(r*(XT+2)+X)*IC8 + k] = z;
  }
  // interior: per-wave 64-chunk contiguous LDS runs via global_load_lds;
  // XOR swizzle folded into the per-lane GLOBAL source address
  for(int c0=0; c0<4*ROW; c0+=256){
    int cw  = c0 + w*64;              // wave-uniform chunk base
    int r   = cw / ROW;               // uniform per wave (64 | ROW)
    int rem = cw % ROW;
    int gy  = 2*py - 1 + r;
    int ldsbase = (r*(XT+2)+1)*IC8 + rem;
    if((unsigned)gy < (unsigned)HW){
      int remL = rem + lane;
      int x = remL / IC8, k = remL % IC8;
      int ksrc = k ^ ((x+1)&SM);
      const bf16* src = in + (((size_t)b*HW + gy)*XT + x)*IC + ksrc*8;
      load_lds16(src, (void*)&T[ldsbase]);
    } else {
      short8 z = {0,0,0,0,0,0,0,0};
      T[ldsbase + lane] = z;
    }
  }
  __syncthreads();

  float bv[WNF];
  #pragma unroll
  for(int n=0;n<WNF;n++) bv[n] = bias[nbase + n*16 + l15];
  f32x4 acc[2][2][WNF];
  #pragma unroll
  for(int r=0;r<2;r++)
  #pragma unroll
  for(int m=0;m<2;m++)
  #pragma unroll
  for(int n=0;n<WNF;n++){
    acc[r][m][n][0]=bv[n]; acc[r][m][n][1]=bv[n];
    acc[r][m][n][2]=bv[n]; acc[r][m][n][3]=bv[n];
  }

  const short8* wt8 = (const short8*)wt;
  #pragma unroll
  for(int tap=0; tap<9; tap++){
    const int dy = tap/3 - 1, dx = tap%3 - 1;
    #pragma unroll
    for(int kc=0; kc<KC; kc++){
      short8 Bf[WNF];
      #pragma unroll
      for(int n=0;n<WNF;n++){
        int oc = nbase + n*16 + l15;
        Bf[n] = wt8[(size_t)(tap*OC + oc)*IC8 + kc*4 + lhi];
      }
      short8 Af[2][2];
      #pragma unroll
      for(int r=0;r<2;r++)
      #pragma unroll
      for(int m=0;m<2;m++){
        int X = mbase + m*16 + l15 + dx + 1;
        int rs = r + dy + 1;
        Af[r][m] = T[(rs*(XT+2)+X)*IC8 + ((kc*4+lhi) ^ (X&SM))];
      }
      __builtin_amdgcn_s_setprio(1);
      #pragma unroll
      for(int r=0;r<2;r++)
      #pragma unroll
      for(int m=0;m<2;m++)
      #pragma unroll
      for(int n=0;n<WNF;n++)
        acc[r][m][n] = __builtin_amdgcn_mfma_f32_16x16x32_bf16(Af[r][m], Bf[n], acc[r][m][n], 0,0,0);
      __builtin_amdgcn_s_setprio(0);
    }
  }

  if(POOL){
    constexpr int HP = HW/2;
    #pragma unroll
    for(int m=0;m<2;m++)
    #pragma unroll
    for(int n=0;n<WNF;n++){
      int oc = nbase + n*16 + l15;
      #pragma unroll
      for(int t=0;t<2;t++){
        float v = fmaxf(fmaxf(acc[0][m][n][2*t], acc[0][m][n][2*t+1]),
                        fmaxf(acc[1][m][n][2*t], acc[1][m][n][2*t+1]));
        v = fmaxf(v, 0.f);
        int xp = (mbase + m*16)/2 + lhi*2 + t;
        out[(((size_t)b*HP + py)*HP + xp)*OC + oc] = f2b(v);
      }
    }
  } else {
    // fused relu + spatial sum (this block's 2 rows x 32 x) -> partial2[b*16+py][oc]
    #pragma unroll
    for(int n=0;n<WNF;n++){
      float p = 0.f;
      #pragma unroll
      for(int r=0;r<2;r++)
      #pragma unroll
      for(int m=0;m<2;m++)
      #pragma unroll
      for(int j=0;j<4;j++)
        p += fmaxf(acc[r][m][n][j], 0.f);
      p += __shfl_xor(p, 16);
      p += __shfl_xor(p, 32);
      if(lhi == 0)
        partial2[((size_t)(b*16+py))*256 + nbase + n*16 + l15] = p;
    }
  }
}

// ---------- headA: feat = mean(partial2, 16 q) in LDS; nd1(512) + cp1(256), wave-per-output
__global__ __launch_bounds__(256) void k_headA(const float* __restrict__ partial2,
                      const float* __restrict__ nd1w, const float* __restrict__ nd1b,
                      const float* __restrict__ cp1w, const float* __restrict__ cp1b,
                      float* __restrict__ h512, float* __restrict__ h256){
  __shared__ float F[256];
  int b = blockIdx.x / 192, blk = blockIdx.x % 192;
  int tid = threadIdx.x;
  float s = 0.f;
  #pragma unroll
  for(int q=0;q<16;q++) s += partial2[((size_t)(b*16+q))*256 + tid];
  F[tid] = s * (1.f/1024.f);
  __syncthreads();
  int w = tid>>6, lane = tid&63;
  int o = blk*4 + w;
  float4 xv = ((const float4*)F)[lane];
  const float* wrow; float bb; float* dst; int oo;
  if(o < 512){ wrow = nd1w + (size_t)o*256; bb = nd1b[o]; dst = h512 + b*512 + o; }
  else { oo = o - 512; wrow = cp1w + (size_t)oo*256; bb = cp1b[oo]; dst = h256 + b*256 + oo; }
  float a = dot4(((const float4*)wrow)[lane], xv);
  #pragma unroll
  for(int off=32; off>0; off>>=1) a += __shfl_xor(a, off);
  if(lane==0) *dst = fmaxf(a + bb, 0.f);
}

// ---------- node mask dtype helpers (prefix mask)
__device__ __forceinline__ int mask_mode(const void* p){
  unsigned w0 = ((const unsigned*)p)[0];
  unsigned w1 = ((const unsigned*)p)[1];
  if(w0 == 1u) return (w1 == 0u) ? 4 : 0;
  if(w0 == 0x3F800000u) return 3;
  unsigned short h0 = (unsigned short)(w0 & 0xFFFFu);
  if(h0 == 0x3F80u || h0 == 0x3C00u) return 2;
  return 1;
}
__device__ __forceinline__ int mask_get(const void* p, int i, int mode){
  switch(mode){
    case 0: return ((const int*)p)[i] != 0;
    case 1: return ((const unsigned char*)p)[i] != 0;
    case 2: return ((const unsigned short*)p)[i] != 0;
    case 3: return ((const float*)p)[i] != 0.f;
    default: return ((const long long*)p)[i] != 0ll;
  }
}

// ---------- headB: nd2 (700 -> coords) + cp2 (count) + per-batch mask counts
__global__ __launch_bounds__(256) void k_headB(const float* __restrict__ h512,
                      const float* __restrict__ h256,
                      const float* __restrict__ nd2w, const float* __restrict__ nd2b,
                      const float* __restrict__ cp2w, const float* __restrict__ cp2b,
                      const void* __restrict__ masks,
                      float* __restrict__ coordsOut, float* __restrict__ countOut,
                      int* __restrict__ counts){
  int b = blockIdx.x / 176, blk = blockIdx.x % 176;
  int tid = threadIdx.x;
  int w = tid>>6, lane = tid&63;
  int o = blk*4 + w;
  if(o == 701){
    int mode = mask_mode(masks);
    int c = 0;
    for(int i=lane; i<350; i+=64) c += mask_get(masks, b*350+i, mode);
    #pragma unroll
    for(int off=32; off>0; off>>=1) c += __shfl_xor(c, off);
    if(lane==0) counts[b] = c;
    return;
  }
  if(o > 700) return;
  float a;
  if(o < 700){
    const float4* xp = (const float4*)(h512 + b*512);
    const float4* wp = (const float4*)(nd2w + (size_t)o*512);
    a = dot4(wp[lane], xp[lane]) + dot4(wp[lane+64], xp[lane+64]);
  } else {
    const float4* xp = (const float4*)(h256 + b*256);
    const float4* wp = (const float4*)cp2w;
    a = dot4(wp[lane], xp[lane]);
  }
  #pragma unroll
  for(int off=32; off>0; off>>=1) a += __shfl_xor(a, off);
  if(lane==0){
    if(o < 700) coordsOut[b*700 + o] = a + nd2b[o];
    else        countOut[b] = a + cp2b[0];
  }
}

// ---------- adjacency: 4 outputs/thread, rsqrt normalize + LUT lerp + prefix-count gate
__global__ __launch_bounds__(256) void k_adj(const float* __restrict__ coords,
                      const int* __restrict__ counts, const float* __restrict__ lut,
                      float* __restrict__ out){
  int t4 = blockIdx.x*256 + threadIdx.x;
  if(t4 >= 490000) return;
  int base = t4*4;
  int b = base / 122500;
  int rem = base % 122500;     // 122500 % 4 == 0: all 4 elems share b
  int cnt = counts[b];
  int valid = cnt > 1;
  float res[4];
  #pragma unroll
  for(int e=0;e<4;e++){
    int n = (rem+e)/350, m = (rem+e)%350;
    float o = 0.f;
    if(valid && n < cnt && m < cnt){
      float2 a = ((const float2*)coords)[b*350+n];
      float2 c = ((const float2*)coords)[b*350+m];
      float nn = fmaxf(fmaf(a.x,a.x, a.y*a.y), 1e-24f);
      float mm = fmaxf(fmaf(c.x,c.x, c.y*c.y), 1e-24f);
      float s = fmaf(a.x, c.x, a.y*c.y) * __frsqrt_rn(nn) * __frsqrt_rn(mm);
      float u = (s + 1.f) * 2047.5f;
      u = fminf(fmaxf(u, 0.f), 4095.f);
      int i = min((int)u, 4094);
      float fr = u - (float)i;
      float l0 = lut[i], l1 = lut[i+1];
      o = fmaf(l1 - l0, fr, l0);
    }
    res[e] = o;
  }
  *(float4*)(out + base) = make_float4(res[0], res[1], res[2], res[3]);
}

extern "C" void kernel_launch(void* const* d_in, const int* in_sizes, int n_in,
                              void* d_out, int out_size, void* d_ws, size_t ws_size,
                              hipStream_t stream){
  const float* images = (const float*)d_in[0];
  const void*  masks  = d_in[1];
  const float *c1w=(const float*)d_in[2],  *c1b=(const float*)d_in[3];
  const float *c2w=(const float*)d_in[4],  *c2b=(const float*)d_in[5];
  const float *c3w=(const float*)d_in[6],  *c3b=(const float*)d_in[7];
  const float *c4w=(const float*)d_in[8],  *c4b=(const float*)d_in[9];
  const float *nd1w=(const float*)d_in[10],*nd1b=(const float*)d_in[11];
  const float *nd2w=(const float*)d_in[12],*nd2b=(const float*)d_in[13];
  const float *cp1w=(const float*)d_in[14],*cp1b=(const float*)d_in[15];
  const float *cp2w=(const float*)d_in[16],*cp2b=(const float*)d_in[17];
  const float *mc1w=(const float*)d_in[18],*mc1b=(const float*)d_in[19];
  const float *mc2w=(const float*)d_in[20],*mc2b=(const float*)d_in[21];
  const float *mc3w=(const float*)d_in[22],*mc3b=(const float*)d_in[23];
  float* out = (float*)d_out;   // f32: coords[11200] | adjacency[1960000] | count[16]

  // ---- workspace
  char* W = (char*)d_ws;
  float* partial2 = (float*)W;                  // 256 rows x 256 f32 = 256 KB @0
  float* h512     = (float*)(W + 262144);       // 8192 f32 (32 KB)
  float* h256     = (float*)(W + 294912);       // 4096 f32 (16 KB)
  float* lut      = (float*)(W + 311296);       // 4096 f32 (16 KB)
  int*   counts   = (int*)(W + 327680);         // 64 B
  bf16*  wt2 = (bf16*)(W + 524288);             // 18432 bf16 (36 KB)
  bf16*  wt3 = (bf16*)(W + 589824);             // 73728 bf16 (144 KB)
  bf16*  wt4 = (bf16*)(W + 786432);             // 294912 bf16 (576 KB)
  bf16*  x1 = (bf16*)(W + 2097152);             // [16][128][128][32] 16.78 MB
  bf16*  x2 = (bf16*)(W + 2097152 + 16777216);  // [16][64][64][64]    8.39 MB
  bf16*  x3 = (bf16*)(W + 2097152);             // [16][32][32][128]   4.19 MB (reuse x1)

  float* coordsOut = out;
  float* adjOut    = out + 11200;
  float* countOut  = out + 11200 + 1960000;

  k_c1prep<<<2552, 256, 0, stream>>>(images, c1w, c1b, x1,
                                     c2w, c3w, c4w, wt2, wt3, wt4,
                                     mc1w, mc1b, mc2w, mc2b, mc3w, mc3b, lut);
  k_convmfma<2><<<1024, 256, 0, stream>>>(x1, wt2, c2b, x2, nullptr);
  k_convmfma<3><<<512, 256, 0, stream>>>(x2, wt3, c3b, x3, nullptr);
  k_convmfma<4><<<512, 256, 0, stream>>>(x3, wt4, c4b, nullptr, partial2);
  k_headA<<<3072, 256, 0, stream>>>(partial2, nd1w, nd1b, cp1w, cp1b, h512, h256);
  k_headB<<<2816, 256, 0, stream>>>(h512, h256, nd2w, nd2b, cp2w, cp2b, masks,
                                    coordsOut, countOut, counts);
  k_adj<<<1915, 256, 0, stream>>>(coordsOut, counts, lut, adjOut);
}